// Round 8
// baseline (269.679 us; speedup 1.0000x reference)
//
#include <hip/hip_runtime.h>
#include <math.h>

typedef unsigned short u16;
typedef __attribute__((ext_vector_type(8))) short bf16x8;
typedef __attribute__((ext_vector_type(4))) float f32x4;

#define D_MODEL 256
#define T_SZ 1024
constexpr size_t S_ELT = (size_t)8192 * 256;
constexpr size_t MB = 1024 * 1024;

// workspace byte offsets (56MB footprint)
constexpr size_t OFF_QKV = 0;          // u16 [8192][768] (12MB); later f overlays [0,16MB)
constexpr size_t OFF_ATTN = 12 * MB;   // u16 [8192][256] (4MB); later states_bf
constexpr size_t OFF_F = 0;            // u16 [8192][1024] (16MB)
constexpr size_t OFF_X = 16 * MB;      // f32 [8192][256] (8MB)
constexpr size_t OFF_COMB = 24 * MB;   // u16 [8192][768] (12MB); col 0-255 = bf16 x (live to ffn1)
constexpr size_t OFF_FB = 36 * MB;     // f32 [8192][256]: deltas (cumsummed in t2 epilogue)
constexpr size_t OFF_H = 44 * MB;      // u16: vt (4MB, dead after attn) then h (8MB)
constexpr size_t OFF_WB = 52 * MB;     // u16 weights (2.75MB)
constexpr int WB_INPROJ = 0;
constexpr int WB_OUTPROJ = 196608;
constexpr int WB_P2S = 262144;
constexpr int WB_S2P = 327680;
constexpr int WB_T1 = 393216;
constexpr int WB_T2 = 786432;
constexpr int WB_F1 = 917504;
constexpr int WB_F2 = 1179648;
constexpr int WB_TOTAL = 1441792;
constexpr int PR_TOTAL = 2097152;
constexpr size_t OFF_B1E = OFF_WB + (size_t)WB_TOTAL * 2;  // f32 512 (t1 bias fold)
constexpr size_t OFF_B1E2 = OFF_B1E + 4096;                // f32 1024 (ffn1 bias fold)
constexpr size_t OFF_WC2 = 55 * MB;                        // u16 1024x256 (0.3*F1@S2P)
constexpr size_t OFF_SCR1 = 55 * MB + 524288;              // f32 65536 (chunk EMAs)
constexpr size_t OFF_SCR2 = 55 * MB + 786432;              // f32 65536 (chunk totals)

__device__ __forceinline__ u16 f2bf(float f) {
  unsigned int u = __float_as_uint(f);
  u += 0x7fff + ((u >> 16) & 1);
  return (u16)(u >> 16);
}
__device__ __forceinline__ float bf2f(u16 s) {
  return __uint_as_float(((unsigned int)s) << 16);
}

// async global -> LDS, 16B per lane; LDS dst is wave-uniform base + lane*16B.
__device__ __forceinline__ void glds16(const u16* g, u16* l) {
  __builtin_amdgcn_global_load_lds(
      (const __attribute__((address_space(1))) void*)g,
      (__attribute__((address_space(3))) void*)l, 16, 0, 0);
}

// ---------------------------------------------------------------------------
// Merged weight prep (role-split dispatch):
//  blocks 0-3455    : fp32->bf16 conversion of weights + parallel_repr.
//                     Skips T1's k<256 region (the fold role writes it —
//                     disjoint writes, so no ordering needed).
//  blocks 3456-3519 : t1 fold  W1eff = t1_x + 0.3*t1_x@P2S  (k<256 cols)
//  blocks 3520-3647 : ffn fold Wc2 = 0.3*F1@S2P  (+ bias folds)
// ---------------------------------------------------------------------------
__global__ __launch_bounds__(256)
void wprep_kernel(const float* w0, const float* w1, const float* w2,
                  const float* w3, const float* w4, const float* w5,
                  const float* w6, const float* w7, const float* pr,
                  u16* __restrict__ wb, u16* __restrict__ prb,
                  const float* __restrict__ t1b, const float* __restrict__ p2sb,
                  const float* __restrict__ f1b, const float* __restrict__ s2pb,
                  float* __restrict__ b1e, u16* __restrict__ wc2,
                  float* __restrict__ b1e2) {
  __shared__ float trow[8][256];  // 8KB (fold roles only)
  const int bx = blockIdx.x;
  if (bx < 3456) {
    const int idx4 = (bx * 256 + threadIdx.x) * 4;
    if (idx4 < WB_TOTAL) {
      const int offs[9] = {WB_INPROJ, WB_OUTPROJ, WB_P2S,  WB_S2P, WB_T1,
                           WB_T2,     WB_F1,      WB_F2,   WB_TOTAL};
      const float* srcs[8] = {w0, w1, w2, w3, w4, w5, w6, w7};
      int seg = 0;
      while (idx4 >= offs[seg + 1]) ++seg;
      const bool skip = (seg == 4) && (((idx4 - WB_T1) % 768) < 256);
      if (!skip) {
        float4 v = *(const float4*)(srcs[seg] + (idx4 - offs[seg]));
        unsigned int lo = (unsigned int)f2bf(v.x) | ((unsigned int)f2bf(v.y) << 16);
        unsigned int hi = (unsigned int)f2bf(v.z) | ((unsigned int)f2bf(v.w) << 16);
        *(uint2*)(wb + idx4) = make_uint2(lo, hi);
      }
    } else {
      const int i4 = idx4 - WB_TOTAL;
      if (i4 < PR_TOTAL) {
        float4 v = *(const float4*)(pr + i4);
        unsigned int lo = (unsigned int)f2bf(v.x) | ((unsigned int)f2bf(v.y) << 16);
        unsigned int hi = (unsigned int)f2bf(v.z) | ((unsigned int)f2bf(v.w) << 16);
        *(uint2*)(prb + i4) = make_uint2(lo, hi);
      }
    }
  } else {
    const int blk = bx - 3456;
    const int k = threadIdx.x;
    const bool t1role = blk < 64;
    const int o0 = t1role ? blk * 8 : (blk - 64) * 8;
    const float* wsrc = t1role ? w4 : w6;   // trans_w1 / ffn_w1 (fp32)
    const int wstride = t1role ? 768 : 256;
    const float* psrc = t1role ? w2 : w3;   // p2s_w / s2p_w (fp32)
    const float* pbsrc = t1role ? p2sb : s2pb;
#pragma unroll
    for (int r = 0; r < 8; ++r)
      trow[r][k] = wsrc[(size_t)(o0 + r) * wstride + k];
    __syncthreads();
    float acc[8] = {};
    float bacc[8] = {};
    for (int i = 0; i < 256; ++i) {
      const float pv = psrc[(size_t)i * 256 + k];
      const float pbv = pbsrc[i];
#pragma unroll
      for (int r = 0; r < 8; ++r) {
        acc[r] = fmaf(trow[r][i], pv, acc[r]);
        bacc[r] = fmaf(trow[r][i], pbv, bacc[r]);
      }
    }
    if (t1role) {
      u16* wt1 = wb + WB_T1;
#pragma unroll
      for (int r = 0; r < 8; ++r)
        wt1[(size_t)(o0 + r) * 768 + k] = f2bf(trow[r][k] + 0.3f * acc[r]);
      if (k == 0) {
#pragma unroll
        for (int r = 0; r < 8; ++r)
          b1e[o0 + r] = t1b[o0 + r] + 0.3f * bacc[r];
      }
    } else {
#pragma unroll
      for (int r = 0; r < 8; ++r)
        wc2[(size_t)(o0 + r) * 256 + k] = f2bf(0.3f * acc[r]);
      if (k == 0) {
#pragma unroll
        for (int r = 0; r < 8; ++r)
          b1e2[o0 + r] = f1b[o0 + r] + 0.3f * bacc[r];
      }
    }
  }
}

// ---------------------------------------------------------------------------
// bf16 MFMA GEMM, pipelined double-buffered LDS staging.
// SPLIT: k<256 reads (A,lda)/(Wb,ldb); k>=256 reads (A2,256)/(B2,256).
// VSPLIT (in_proj): cols >=512 (V) are written transposed to vt instead.
// CSUM (t2 only, BM=64, fp32 out): epilogue computes the per-32-row-chunk
// cumsum in registers (lane prefix -> quad shfl prefix -> cross-wave LDS
// base) and writes cumsummed deltas + raw chunk totals (kills cs_a).
// ---------------------------------------------------------------------------
enum { EPI_NONE = 0, EPI_GELU = 1 };

template <int EPI, int BM, int BN, bool OUTBF, bool VSPLIT, bool SPLIT, bool CSUM>
__global__ __launch_bounds__(256, 4)
void mgemm(const u16* __restrict__ A, int lda, const u16* __restrict__ A2,
           const u16* __restrict__ Wb, int ldb, const u16* __restrict__ B2,
           int K, const float* __restrict__ bias, void* __restrict__ Cv,
           int ldc, int col_off, u16* __restrict__ vt,
           float* __restrict__ csum) {
  __shared__ u16 As[2 * BM * 64];
  __shared__ u16 Bs[2 * BN * 64];
  const int tid = threadIdx.x;
  const int w = tid >> 6, lane = tid & 63;
  const int ln = lane & 15, quad = lane >> 4;
  const int m0 = blockIdx.x * BM;
  const int n0 = blockIdx.y * BN;
  constexpr int MT = (BM == 128) ? 2 : 1;  // wave rows = 4 waves x (MT*16)
  const int wm = w * (MT * 16);
  constexpr int APW = BM / 64;  // A 16-row groups per wave per sub-step
  constexpr int BPW = BN / 64;

  f32x4 acc[MT][4] = {};

  const int grow = lane >> 2;      // row within 16-row group
  const int gk8 = (lane & 3) * 8;  // k element offset

#define STAGE_MM(k0s, buf)                                                    \
  {                                                                           \
    const u16* Ag; const u16* Bg; int as_, bs_, kk;                           \
    if (!SPLIT || (k0s) < 256) {                                              \
      Ag = A; as_ = lda; Bg = Wb; bs_ = ldb; kk = (k0s);                      \
    } else {                                                                  \
      Ag = A2; as_ = 256; Bg = B2; bs_ = 256; kk = (k0s)-256;                 \
    }                                                                         \
    _Pragma("unroll") for (int s = 0; s < 2; ++s) {                           \
      _Pragma("unroll") for (int p = 0; p < APW; ++p) {                       \
        const int g = w * APW + p;                                            \
        glds16(Ag + (size_t)(m0 + g * 16 + grow) * as_ + kk + s * 32 + gk8,   \
               As + (buf) * (BM * 64) + s * BM * 32 + g * 512);               \
      }                                                                       \
      _Pragma("unroll") for (int p = 0; p < BPW; ++p) {                       \
        const int g = w * BPW + p;                                            \
        glds16(Bg + (size_t)(n0 + g * 16 + grow) * bs_ + kk + s * 32 + gk8,   \
               Bs + (buf) * (BN * 64) + s * BN * 32 + g * 512);               \
      }                                                                       \
    }                                                                         \
  }

  int cur = 0;
  STAGE_MM(0, 0);
  for (int k0 = 0; k0 < K; k0 += 64) {
    __syncthreads();  // buf[cur] valid (per-wave vmcnt drained at barrier)
    if (k0 + 64 < K) STAGE_MM(k0 + 64, cur ^ 1);  // in flight across compute
#pragma unroll
    for (int s = 0; s < 2; ++s) {
      const u16* abase =
          As + cur * (BM * 64) + s * BM * 32 + (wm >> 4) * 512 + ln * 32 + quad * 8;
      const u16* bbase = Bs + cur * (BN * 64) + s * BN * 32 + ln * 32 + quad * 8;
      bf16x8 af[MT], bv[4];
#pragma unroll
      for (int i = 0; i < MT; ++i) af[i] = *(const bf16x8*)(abase + i * 512);
#pragma unroll
      for (int j = 0; j < 4; ++j) bv[j] = *(const bf16x8*)(bbase + j * 512);
#pragma unroll
      for (int i = 0; i < MT; ++i)
#pragma unroll
        for (int j = 0; j < 4; ++j)
          acc[i][j] = __builtin_amdgcn_mfma_f32_16x16x32_bf16(af[i], bv[j],
                                                              acc[i][j], 0, 0, 0);
    }
    cur ^= 1;
  }
#undef STAGE_MM

  if constexpr (CSUM) {
    // chunk cumsum epilogue: chunk0 = waves 0,1 (rows m0..m0+31),
    // chunk1 = waves 2,3. Per column: lane prefix over 4 rows, quad
    // prefix via shfl_up, cross-wave half base via LDS.
    __shared__ float halfsum[4][64];
    const int row0 = m0 + wm + quad * 4;
    float lp[4][4], qex[4];
#pragma unroll
    for (int j = 0; j < 4; ++j) {
      const float bsv = bias[n0 + j * 16 + ln];
      float run = 0.f;
#pragma unroll
      for (int r = 0; r < 4; ++r) {
        run += acc[0][j][r] + bsv;
        lp[j][r] = run;
      }
      float sq = run;  // lane total (4 rows)
      float u = __shfl_up(sq, 16);
      if (quad >= 1) sq += u;
      u = __shfl_up(sq, 32);
      if (quad >= 2) sq += u;
      qex[j] = sq - run;  // exclusive prefix of quads below
      if (quad == 3) halfsum[w][j * 16 + ln] = sq;  // wave (16-row) total
    }
    __syncthreads();
#pragma unroll
    for (int j = 0; j < 4; ++j) {
      const float base = (w & 1) ? halfsum[w - 1][j * 16 + ln] : 0.f;
#pragma unroll
      for (int r = 0; r < 4; ++r)
        ((float*)Cv)[(size_t)(row0 + r) * ldc + n0 + j * 16 + ln] =
            lp[j][r] + qex[j] + base;
    }
    if (tid < 128) {  // raw chunk totals -> scr2
      const int c = tid & 63, chi = tid >> 6;
      const int bb_ = m0 >> 10, ch0 = (m0 & 1023) >> 5;
      csum[(size_t)(bb_ * 32 + ch0 + chi) * 256 + n0 + c] =
          halfsum[2 * chi][c] + halfsum[2 * chi + 1][c];
    }
    return;
  }

#pragma unroll
  for (int i = 0; i < MT; ++i)
#pragma unroll
    for (int j = 0; j < 4; ++j) {
      const int col = n0 + j * 16 + ln;
      const float bsv = bias[col];
      const int row0 = m0 + wm + i * 16 + quad * 4;
      float vals[4];
#pragma unroll
      for (int r = 0; r < 4; ++r) {
        float v = acc[i][j][r] + bsv;
        if (EPI == EPI_GELU) v = 0.5f * v * (1.0f + erff(v * 0.70710678f));
        vals[r] = v;
      }
      if (VSPLIT && col >= 512) {
        // V: write transposed vt[(b*256 + (col-512))][t], 4 consecutive t
        ushort4 pk;
        pk.x = f2bf(vals[0]); pk.y = f2bf(vals[1]);
        pk.z = f2bf(vals[2]); pk.w = f2bf(vals[3]);
        *(ushort4*)(vt + (size_t)((row0 >> 10) * 256 + (col - 512)) * T_SZ +
                    (row0 & 1023)) = pk;
      } else if (OUTBF) {
#pragma unroll
        for (int r = 0; r < 4; ++r)
          ((u16*)Cv)[(size_t)(row0 + r) * ldc + col_off + col] = f2bf(vals[r]);
      } else {
#pragma unroll
        for (int r = 0; r < 4; ++r)
          ((float*)Cv)[(size_t)(row0 + r) * ldc + col_off + col] = vals[r];
      }
    }
}

// ---------------------------------------------------------------------------
// Fused GEMM (+add) + LayerNorm epilogue, pipelined double-buffered staging.
// BM=16, BN=256 (full row), grid = 512 blocks (2/CU; 68KB LDS). Wave w owns
// the 64-col slice; LN row-reduction = wave-local shfl + LDS combine.
// ---------------------------------------------------------------------------
template <bool WRITE_BF>
__global__ __launch_bounds__(256, 4)
void mgemm_ln16(const u16* __restrict__ A, const u16* __restrict__ Wb, int K,
                const float* __restrict__ bias, const float* __restrict__ addsrc,
                const float* __restrict__ g, const float* __restrict__ bb,
                float* __restrict__ outf, u16* __restrict__ outbf, int bfldc) {
  __shared__ u16 As[2 * 1024];    // 4KB: [buf][s][16 rows x 32 k]
  __shared__ u16 Bs[2 * 16384];   // 64KB: [buf][s][16 groups][16x32]
  __shared__ float tS1[4][16], tS2[4][16];
  const int tid = threadIdx.x;
  const int w = tid >> 6, lane = tid & 63;
  const int ln = lane & 15, quad = lane >> 4;
  const int m0 = blockIdx.x * 16;
  const int grow = lane >> 2;      // row within 16-row group
  const int gk8 = (lane & 3) * 8;  // k element offset

  f32x4 acc[4] = {};

#define STAGE_LN(k0s, buf)                                                    \
  {                                                                           \
    if (w < 2)                                                                \
      glds16(A + (size_t)(m0 + grow) * K + (k0s) + w * 32 + gk8,              \
             As + (buf) * 1024 + w * 512);                                    \
    _Pragma("unroll") for (int p = 0; p < 8; ++p) {                           \
      const int idx = w * 8 + p;                                              \
      const int s = idx >> 4, gg = idx & 15;                                  \
      glds16(Wb + (size_t)(gg * 16 + grow) * K + (k0s) + s * 32 + gk8,        \
             Bs + (buf) * 16384 + s * 8192 + gg * 512);                       \
    }                                                                         \
  }

  int cur = 0;
  STAGE_LN(0, 0);
  for (int k0 = 0; k0 < K; k0 += 64) {
    __syncthreads();
    if (k0 + 64 < K) STAGE_LN(k0 + 64, cur ^ 1);
#pragma unroll
    for (int s = 0; s < 2; ++s) {
      const bf16x8 af =
          *(const bf16x8*)(As + cur * 1024 + s * 512 + ln * 32 + quad * 8);
      const u16* bbase =
          Bs + cur * 16384 + s * 8192 + (w * 4) * 512 + ln * 32 + quad * 8;
#pragma unroll
      for (int j = 0; j < 4; ++j) {
        bf16x8 bv = *(const bf16x8*)(bbase + j * 512);
        acc[j] = __builtin_amdgcn_mfma_f32_16x16x32_bf16(af, bv, acc[j], 0, 0, 0);
      }
    }
    cur ^= 1;
  }
#undef STAGE_LN

  // epilogue: add bias + addsrc, accumulate LN stats
  const int row0 = m0 + quad * 4;
  float s1[4] = {}, s2[4] = {};
#pragma unroll
  for (int j = 0; j < 4; ++j) {
    const int col = w * 64 + j * 16 + ln;
    const float bsv = bias[col];
#pragma unroll
    for (int r = 0; r < 4; ++r) {
      float v = acc[j][r] + bsv + addsrc[(size_t)(row0 + r) * 256 + col];
      acc[j][r] = v;
      s1[r] += v;
      s2[r] += v * v;
    }
  }
  // wave-local reduce over the 16 ln lanes (quad = row-parallel)
#pragma unroll
  for (int r = 0; r < 4; ++r) {
#pragma unroll
    for (int o = 8; o > 0; o >>= 1) {
      s1[r] += __shfl_xor(s1[r], o);
      s2[r] += __shfl_xor(s2[r], o);
    }
  }
  __syncthreads();
  if (ln == 0) {
#pragma unroll
    for (int r = 0; r < 4; ++r) {
      tS1[w][quad * 4 + r] = s1[r];
      tS2[w][quad * 4 + r] = s2[r];
    }
  }
  __syncthreads();
  float mean[4], inv[4];
#pragma unroll
  for (int r = 0; r < 4; ++r) {
    const int qr = quad * 4 + r;
    const float S1 = tS1[0][qr] + tS1[1][qr] + tS1[2][qr] + tS1[3][qr];
    const float S2 = tS2[0][qr] + tS2[1][qr] + tS2[2][qr] + tS2[3][qr];
    mean[r] = S1 * (1.f / 256.f);
    const float var = S2 * (1.f / 256.f) - mean[r] * mean[r];
    inv[r] = rsqrtf(var + 1e-5f);
  }
#pragma unroll
  for (int j = 0; j < 4; ++j) {
    const int col = w * 64 + j * 16 + ln;
    const float gc = g[col], bc = bb[col];
#pragma unroll
    for (int r = 0; r < 4; ++r) {
      const float y = (acc[j][r] - mean[r]) * inv[r] * gc + bc;
      outf[(size_t)(row0 + r) * 256 + col] = y;
      if (WRITE_BF) outbf[(size_t)(row0 + r) * bfldc + col] = f2bf(y);
    }
  }
}

// ---------------------------------------------------------------------------
// LDS-staged MFMA flash attention (r6, verified). Block = 4 waves = q-tiles
// 4p..4p+3 of one (b,h): equal causal tile counts, shared K/V, double-
// buffered LDS prefetch, one barrier per tile. p paired with 15-p across
// the grid for constant co-resident work.
// ---------------------------------------------------------------------------
__global__ __launch_bounds__(256)
void attn_flash(const u16* __restrict__ qkv, const u16* __restrict__ vt,
                u16* __restrict__ outp) {
  __shared__ u16 Ks[2][4096];   // [buf][s*2048 + g*512 + row*32 + k8]
  __shared__ u16 Vs[2][4096];
  __shared__ u16 Ps[4][16][72];
  const int tid = threadIdx.x;
  const int w = tid >> 6, lane = tid & 63;
  const int ln = lane & 15, quad = lane >> 4, kq8 = quad * 8;
  const int bid = blockIdx.x;
  const int r0 = bid & 255;
  int bh = r0 >> 4;
  int p = r0 & 15;
  if (bid >> 8) { bh += 16; p = 15 - p; }
  const int qt = p * 4 + w;
  const int q0 = qt * 16;
  const int b = bh >> 2, h = bh & 3;
  const u16* base = qkv + (size_t)b * T_SZ * 768;
  const u16* kbase = base + 256 + h * 64;
  const u16* vbase = vt + (size_t)bh * 64 * T_SZ;
  const int grow = lane >> 2;
  const int gk8 = (lane & 3) * 8;

  bf16x8 qf[2];
#pragma unroll
  for (int ks = 0; ks < 2; ++ks)
    qf[ks] = *(const bf16x8*)(base + (size_t)(q0 + ln) * 768 + h * 64 +
                              ks * 32 + kq8);
  const short ob = (short)0x3F80;
  const bf16x8 ones = {ob, ob, ob, ob, ob, ob, ob, ob};

  const int nt = p + 1;

#define STAGE_KV(jt, buf)                                                     \
  {                                                                           \
    const int c0s = (jt) * 64;                                                \
    const int isV = w >> 1, ss = w & 1;                                       \
    _Pragma("unroll") for (int pg = 0; pg < 4; ++pg) {                        \
      if (!isV)                                                               \
        glds16(kbase + (size_t)(c0s + pg * 16 + grow) * 768 + ss * 32 + gk8,  \
               &Ks[buf][ss * 2048 + pg * 512]);                               \
      else                                                                    \
        glds16(vbase + (size_t)(pg * 16 + grow) * T_SZ + c0s + ss * 32 + gk8, \
               &Vs[buf][ss * 2048 + pg * 512]);                               \
    }                                                                         \
  }

  f32x4 O[4] = {};
  f32x4 l_acc = {};
  int cur = 0;
  STAGE_KV(0, 0);
  for (int jt = 0; jt < nt; ++jt) {
    __syncthreads();
    if (jt + 1 < nt) STAGE_KV(jt + 1, cur ^ 1);
    const int c0 = jt * 64;
    f32x4 sv[4] = {};
#pragma unroll
    for (int ks = 0; ks < 2; ++ks)
#pragma unroll
      for (int j = 0; j < 4; ++j) {
        bf16x8 kf = *(const bf16x8*)&Ks[cur][ks * 2048 + j * 512 + ln * 32 + kq8];
        sv[j] = __builtin_amdgcn_mfma_f32_16x16x32_bf16(qf[ks], kf, sv[j], 0, 0, 0);
      }
    const bool need_mask = (jt == nt - 1);
#pragma unroll
    for (int j = 0; j < 4; ++j)
#pragma unroll
      for (int r = 0; r < 4; ++r) {
        float pv = __expf(sv[j][r] * 0.125f);
        if (need_mask && (c0 + j * 16 + ln > q0 + quad * 4 + r)) pv = 0.f;
        Ps[w][quad * 4 + r][j * 16 + ln] = f2bf(pv);
      }
#pragma unroll
    for (int ks = 0; ks < 2; ++ks) {
      bf16x8 pf = *(const bf16x8*)&Ps[w][ln][ks * 32 + kq8];
      l_acc = __builtin_amdgcn_mfma_f32_16x16x32_bf16(pf, ones, l_acc, 0, 0, 0);
#pragma unroll
      for (int j = 0; j < 4; ++j) {
        bf16x8 vf = *(const bf16x8*)&Vs[cur][ks * 2048 + j * 512 + ln * 32 + kq8];
        O[j] = __builtin_amdgcn_mfma_f32_16x16x32_bf16(pf, vf, O[j], 0, 0, 0);
      }
    }
    cur ^= 1;
  }
#undef STAGE_KV

  u16* op = outp + (size_t)b * T_SZ * 256;
#pragma unroll
  for (int r = 0; r < 4; ++r) {
    const float inv = 1.f / l_acc[r];
#pragma unroll
    for (int j = 0; j < 4; ++j)
      op[(size_t)(q0 + quad * 4 + r) * 256 + h * 64 + j * 16 + ln] =
          f2bf(O[j][r] * inv);
  }
}

// ---------------------------------------------------------------------------
// block reduction helpers (fp32)
// ---------------------------------------------------------------------------
__device__ __forceinline__ void block_reduce_2(float& a, float& q, float* tmp) {
#pragma unroll
  for (int o = 32; o > 0; o >>= 1) {
    a += __shfl_down(a, o);
    q += __shfl_down(q, o);
  }
  const int lane = threadIdx.x & 63, wid = threadIdx.x >> 6;
  if (lane == 0) { tmp[wid] = a; tmp[4 + wid] = q; }
  __syncthreads();
  a = tmp[0] + tmp[1] + tmp[2] + tmp[3];
  q = tmp[4] + tmp[5] + tmp[6] + tmp[7];
  __syncthreads();
}

__device__ __forceinline__ float ln_finish(float v, float s1, float s2,
                                           float g, float bb) {
  float mean = s1 * (1.f / 256.f);
  float var = s2 * (1.f / 256.f) - mean * mean;
  return (v - mean) * rsqrtf(var + 1e-5f) * g + bb;
}

// ---------------------------------------------------------------------------
// Fused depthwise conv (window 8) + EMA local pass.
// ---------------------------------------------------------------------------
__global__ __launch_bounds__(256)
void emaconv_kernel(const float* __restrict__ x, const float* __restrict__ cw,
                    const float* __restrict__ cb, u16* __restrict__ comb,
                    float* __restrict__ scr) {
  const int bc = blockIdx.x;
  const int b = bc >> 5, ch = bc & 31;
  const int d = threadIdx.x;
  const int t0 = ch * 32;
  float wreg[8];
#pragma unroll
  for (int j = 0; j < 8; ++j) wreg[j] = cw[d * 8 + j];
  const float bias = cb[d];
  float xw[8];
#pragma unroll
  for (int j = 0; j < 7; ++j) {
    const int ts = t0 - 7 + j;
    xw[j] = (ts >= 0) ? x[(size_t)(b * T_SZ + ts) * 256 + d] : 0.f;
  }
  float c = 0.f;
#pragma unroll
  for (int tl = 0; tl < 32; ++tl) {
    const size_t row = (size_t)(b * T_SZ + t0 + tl);
    xw[7] = x[row * 256 + d];
    float conv = bias;
#pragma unroll
    for (int j = 0; j < 8; ++j) conv = fmaf(xw[j], wreg[j], conv);
    c = 0.9f * c + 0.1f * xw[7];
    comb[row * 768 + 256 + d] = f2bf(conv);
    comb[row * 768 + 512 + d] = f2bf(c);
#pragma unroll
    for (int j = 0; j < 7; ++j) xw[j] = xw[j + 1];
  }
  scr[(size_t)bc * 256 + d] = c;
}

__global__ __launch_bounds__(256)
void ema_b_kernel(float* __restrict__ scr) {
  const int b = blockIdx.x, d = threadIdx.x;
  const float q32 = 0.03433683820292512f;  // 0.9^32
  float carry = 0.f;
  for (int ch = 0; ch < 32; ++ch) {
    const size_t idx = (size_t)(b * 32 + ch) * 256 + d;
    float e = scr[idx];
    scr[idx] = carry;
    carry = e + q32 * carry;
  }
}

// vectorized finalize: 4 rows/block (ushort4/float4), 2048 blocks.
__global__ __launch_bounds__(256)
void ema_c_kernel(u16* __restrict__ comb, const float* __restrict__ scr,
                  float* __restrict__ fts) {
  const int row = blockIdx.x * 4 + (threadIdx.x >> 6);
  const int d4 = (threadIdx.x & 63) * 4;
  const int b = row >> 10, t = row & 1023;
  const int ch = t >> 5, tl = t & 31;
  const float4 cv = *(const float4*)(scr + (size_t)(b * 32 + ch) * 256 + d4);
  const float pw = __powf(0.9f, (float)(tl + 1));
  u16* cp = comb + (size_t)row * 768 + 512 + d4;
  ushort4 lv = *(ushort4*)cp;
  float y0 = fmaf(pw, cv.x, bf2f(lv.x));
  float y1 = fmaf(pw, cv.y, bf2f(lv.y));
  float y2 = fmaf(pw, cv.z, bf2f(lv.z));
  float y3 = fmaf(pw, cv.w, bf2f(lv.w));
  ushort4 ov;
  ov.x = f2bf(y0); ov.y = f2bf(y1); ov.z = f2bf(y2); ov.w = f2bf(y3);
  *(ushort4*)cp = ov;
  if (t == 1023) {  // wave-uniform branch
    float4 fo;
    fo.x = y0; fo.y = y1; fo.z = y2; fo.w = y3;
    *(float4*)(fts + b * 256 + d4) = fo;
  }
}

__global__ __launch_bounds__(256)
void cs_b_kernel(float* __restrict__ scr) {
  const int b = blockIdx.x, d = threadIdx.x;
  float carry = 0.f;
  for (int ch = 0; ch < 32; ++ch) {
    const size_t idx = (size_t)(b * 32 + ch) * 256 + d;
    float e = scr[idx];
    scr[idx] = carry;
    carry += e;
  }
}

// states = LN3(seq + 0.5*(chunk_cumsum + carry)); the t==1023 block also
// computes fss = LN4(states row) in-place (block-uniform branch).
__global__ __launch_bounds__(256)
void ln3_states_kernel(const float* __restrict__ deltas, const float* __restrict__ scr,
                       const float* __restrict__ seq, const float* __restrict__ g3,
                       const float* __restrict__ b3, const float* __restrict__ g4,
                       const float* __restrict__ b4, u16* __restrict__ st,
                       float* __restrict__ fss) {
  __shared__ float tmp[8];
  const int row = blockIdx.x;
  const int b = row >> 10, t = row & 1023;
  const int d = threadIdx.x;
  float v = seq[b * 256 + d] +
            0.5f * (deltas[(size_t)row * 256 + d] +
                    scr[(size_t)(b * 32 + (t >> 5)) * 256 + d]);
  float a = v, q = v * v;
  block_reduce_2(a, q, tmp);
  const float y = ln_finish(v, a, q, g3[d], b3[d]);
  st[(size_t)row * 256 + d] = f2bf(y);
  if (t == 1023) {
    float a2 = y, q2 = y * y;
    block_reduce_2(a2, q2, tmp);
    fss[b * 256 + d] = ln_finish(y, a2, q2, g4[d], b4[d]);
  }
}

// ---------------------------------------------------------------------------
extern "C" void kernel_launch(void* const* d_in, const int* in_sizes, int n_in,
                              void* d_out, int out_size, void* d_ws,
                              size_t ws_size, hipStream_t stream) {
  (void)in_sizes; (void)n_in; (void)out_size; (void)ws_size;
  const float* parallel_repr = (const float*)d_in[0];
  const float* sequential_state = (const float*)d_in[1];
  const float* in_proj_b = (const float*)d_in[4];
  const float* out_proj_b = (const float*)d_in[6];
  const float* conv_w = (const float*)d_in[7];
  const float* conv_b = (const float*)d_in[8];
  const float* p2s_b = (const float*)d_in[10];
  const float* s2p_b = (const float*)d_in[12];
  const float* trans_b1 = (const float*)d_in[14];
  const float* trans_b2 = (const float*)d_in[16];
  const float* ffn_b1 = (const float*)d_in[18];
  const float* ffn_b2 = (const float*)d_in[20];
  const float* ln1_s = (const float*)d_in[21];
  const float* ln1_b = (const float*)d_in[22];
  const float* ln2_s = (const float*)d_in[23];
  const float* ln2_b = (const float*)d_in[24];
  const float* ln3_s = (const float*)d_in[25];
  const float* ln3_b = (const float*)d_in[26];
  const float* ln4_s = (const float*)d_in[27];
  const float* ln4_b = (const float*)d_in[28];

  char* ws = (char*)d_ws;
  u16* qkv_bf = (u16*)(ws + OFF_QKV);
  u16* attn_bf = (u16*)(ws + OFF_ATTN);
  u16* states_bf = (u16*)(ws + OFF_ATTN);
  u16* f_bf = (u16*)(ws + OFF_F);
  float* x = (float*)(ws + OFF_X);
  u16* comb = (u16*)(ws + OFF_COMB);
  u16* pr_bf = (u16*)(ws + OFF_COMB);  // dead before comb is written
  float* fbuf = (float*)(ws + OFF_FB);
  u16* vt = (u16*)(ws + OFF_H);        // dead before h is written
  u16* h_bf = (u16*)(ws + OFF_H);
  u16* wb = (u16*)(ws + OFF_WB);
  u16* wc2 = (u16*)(ws + OFF_WC2);
  float* scr1 = (float*)(ws + OFF_SCR1);
  float* scr2 = (float*)(ws + OFF_SCR2);
  float* b1e = (float*)(ws + OFF_B1E);
  float* b1e2 = (float*)(ws + OFF_B1E2);
  float* out = (float*)d_out;
  float* out_fss = out + S_ELT;
  float* out_fts = out + S_ELT + 2048;

  const dim3 blk(256);

  // 0. merged weight prep: bf16 conversion + p2s/s2p weight folds
  wprep_kernel<<<3648, blk, 0, stream>>>(
      (const float*)d_in[3], (const float*)d_in[5], (const float*)d_in[9],
      (const float*)d_in[11], (const float*)d_in[13], (const float*)d_in[15],
      (const float*)d_in[17], (const float*)d_in[19], parallel_repr, wb, pr_bf,
      trans_b1, p2s_b, ffn_b1, s2p_b, b1e, wc2, b1e2);
  // 1. qkv = PR @ in_proj^T + b; V columns written transposed to vt
  mgemm<EPI_NONE, 128, 64, true, true, false, false>
      <<<dim3(64, 12), blk, 0, stream>>>(pr_bf, 256, nullptr, wb + WB_INPROJ,
                                         256, nullptr, 256, in_proj_b, qkv_bf,
                                         768, 0, vt, nullptr);
  // 2. attention (LDS double-buffered K/V prefetch, 4 q-tiles/block)
  attn_flash<<<512, blk, 0, stream>>>(qkv_bf, vt, attn_bf);
  // 3. x = LN1(PR + attn @ out_proj^T + b) -> x fp32 + bf16 mirror into
  //    comb[:,0:256]
  mgemm_ln16<true><<<512, blk, 0, stream>>>(
      attn_bf, wb + WB_OUTPROJ, 256, out_proj_b, parallel_repr, ln1_s, ln1_b,
      x, comb, 768);
  // 4-6. fused conv+EMA -> comb[:,256:768] + traj summary
  emaconv_kernel<<<256, blk, 0, stream>>>(x, conv_w, conv_b, comb, scr1);
  ema_b_kernel<<<8, blk, 0, stream>>>(scr1);
  ema_c_kernel<<<2048, blk, 0, stream>>>(comb, scr1, out_fts);
  // 7. h = gelu(comb @ W1eff^T + b1eff)
  mgemm<EPI_GELU, 128, 64, true, false, false, false>
      <<<dim3(64, 8), blk, 0, stream>>>(comb, 768, nullptr, wb + WB_T1, 768,
                                        nullptr, 768, b1e, h_bf, 512, 0,
                                        nullptr, nullptr);
  // 8. deltas = cumsum_chunk(h @ t2^T + b2) -> fbuf; chunk totals -> scr2
  mgemm<EPI_NONE, 64, 64, false, false, false, true>
      <<<dim3(128, 4), blk, 0, stream>>>(h_bf, 512, nullptr, wb + WB_T2, 512,
                                         nullptr, 512, trans_b2, fbuf, 256, 0,
                                         nullptr, scr2);
  // 9. cross-chunk exclusive scan of totals
  cs_b_kernel<<<8, blk, 0, stream>>>(scr2);
  // 10. states = LN3(...) -> bf16; t==1023 blocks also emit fss = LN4
  ln3_states_kernel<<<8192, blk, 0, stream>>>(fbuf, scr2, sequential_state,
                                              ln3_s, ln3_b, ln4_s, ln4_b,
                                              states_bf, out_fss);
  // 11. f = gelu(x@F1^T + states@Wc2^T + b1e2)  (s2p folded; split-K)
  mgemm<EPI_GELU, 128, 64, true, false, true, false>
      <<<dim3(64, 16), blk, 0, stream>>>(comb, 768, states_bf, wb + WB_F1, 256,
                                         wc2, 512, b1e2, f_bf, 1024, 0,
                                         nullptr, nullptr);
  // 12. out = LN2(x + f @ ffn2^T + b2), fused GEMM+LN
  mgemm_ln16<false><<<512, blk, 0, stream>>>(
      f_bf, wb + WB_F2, 1024, ffn_b2, x, ln2_s, ln2_b, out, nullptr, 256);
}

// Round 9
// 258.777 us; speedup vs baseline: 1.0421x; 1.0421x over previous
//
#include <hip/hip_runtime.h>
#include <math.h>

typedef unsigned short u16;
typedef __attribute__((ext_vector_type(8))) short bf16x8;
typedef __attribute__((ext_vector_type(4))) float f32x4;

#define D_MODEL 256
#define T_SZ 1024
constexpr size_t S_ELT = (size_t)8192 * 256;
constexpr size_t MB = 1024 * 1024;

// workspace byte offsets (56MB footprint)
constexpr size_t OFF_QKV = 0;          // u16 [8192][768] (12MB); later f overlays [0,16MB)
constexpr size_t OFF_ATTN = 12 * MB;   // u16 [8192][256] (4MB); later states_bf
constexpr size_t OFF_F = 0;            // u16 [8192][1024] (16MB)
constexpr size_t OFF_X = 16 * MB;      // f32 [8192][256] (8MB)
constexpr size_t OFF_COMB = 24 * MB;   // u16 [8192][768] (12MB); col 0-255 = bf16 x
constexpr size_t OFF_FB = 36 * MB;     // f32 [8192][256]: deltas
constexpr size_t OFF_H = 44 * MB;      // u16: vt (4MB, dead after attn) then h (8MB)
constexpr size_t OFF_XBF = 48 * MB;    // u16 ffn_in (4MB)
constexpr size_t OFF_WB = 52 * MB;     // u16 weights (2.75MB)
constexpr size_t OFF_SCR1 = 55 * MB;            // f32 65536 (chunk EMAs)
constexpr size_t OFF_SCR2 = 55 * MB + 262144;   // f32 65536 (chunk totals)
constexpr size_t OFF_B1E = 55 * MB + 524288;    // f32 512 (folded trans_b1)

// bf16 weight element offsets inside WB
constexpr int WB_INPROJ = 0;
constexpr int WB_OUTPROJ = 196608;
constexpr int WB_P2S = 262144;
constexpr int WB_S2P = 327680;
constexpr int WB_T1 = 393216;
constexpr int WB_T2 = 786432;
constexpr int WB_F1 = 917504;
constexpr int WB_F2 = 1179648;
constexpr int WB_TOTAL = 1441792;
constexpr int PR_TOTAL = 2097152;

__device__ __forceinline__ u16 f2bf(float f) {
  unsigned int u = __float_as_uint(f);
  u += 0x7fff + ((u >> 16) & 1);
  return (u16)(u >> 16);
}
__device__ __forceinline__ float bf2f(u16 s) {
  return __uint_as_float(((unsigned int)s) << 16);
}

// async global -> LDS, 16B per lane; LDS dst is wave-uniform base + lane*16B.
__device__ __forceinline__ void glds16(const u16* g, u16* l) {
  __builtin_amdgcn_global_load_lds(
      (const __attribute__((address_space(1))) void*)g,
      (__attribute__((address_space(3))) void*)l, 16, 0, 0);
}

// ---------------------------------------------------------------------------
// weight + parallel_repr fp32 -> bf16 conversion (single kernel)
// ---------------------------------------------------------------------------
__global__ __launch_bounds__(256)
void wconv_kernel(const float* w0, const float* w1, const float* w2,
                  const float* w3, const float* w4, const float* w5,
                  const float* w6, const float* w7, const float* pr,
                  u16* __restrict__ wb, u16* __restrict__ prb) {
  const int idx4 = (blockIdx.x * 256 + threadIdx.x) * 4;
  if (idx4 < WB_TOTAL) {
    const int offs[9] = {WB_INPROJ, WB_OUTPROJ, WB_P2S,  WB_S2P, WB_T1,
                         WB_T2,     WB_F1,      WB_F2,   WB_TOTAL};
    const float* srcs[8] = {w0, w1, w2, w3, w4, w5, w6, w7};
    int seg = 0;
    while (idx4 >= offs[seg + 1]) ++seg;
    float4 v = *(const float4*)(srcs[seg] + (idx4 - offs[seg]));
    unsigned int lo = (unsigned int)f2bf(v.x) | ((unsigned int)f2bf(v.y) << 16);
    unsigned int hi = (unsigned int)f2bf(v.z) | ((unsigned int)f2bf(v.w) << 16);
    *(uint2*)(wb + idx4) = make_uint2(lo, hi);
  } else {
    const int i4 = idx4 - WB_TOTAL;
    if (i4 < PR_TOTAL) {
      float4 v = *(const float4*)(pr + i4);
      unsigned int lo = (unsigned int)f2bf(v.x) | ((unsigned int)f2bf(v.y) << 16);
      unsigned int hi = (unsigned int)f2bf(v.z) | ((unsigned int)f2bf(v.w) << 16);
      *(uint2*)(prb + i4) = make_uint2(lo, hi);
    }
  }
}

// ---------------------------------------------------------------------------
// p2s weight fold: W1eff[o][k] = t1[o][k] + 0.3*sum_i t1[o][i]*P[i][k]
// (k<256, o<512), written bf16 into the WB_T1 slot (row stride 768).
// Also b1eff[o] = trans_b1[o] + 0.3*sum_i t1[o][i]*p2s_b[i].
// ---------------------------------------------------------------------------
__global__ __launch_bounds__(256)
void wfold_kernel(const float* __restrict__ t1, const float* __restrict__ p2s,
                  const float* __restrict__ t1b, const float* __restrict__ p2sb,
                  u16* __restrict__ wt1, float* __restrict__ b1e) {
  __shared__ float trow[8][256];  // 8KB
  const int o0 = blockIdx.x * 8;
  const int k = threadIdx.x;
#pragma unroll
  for (int r = 0; r < 8; ++r)
    trow[r][k] = t1[(size_t)(o0 + r) * 768 + k];
  __syncthreads();
  float acc[8] = {};
  float bacc[8] = {};
  for (int i = 0; i < 256; ++i) {
    const float pv = p2s[(size_t)i * 256 + k];
    const float pbv = p2sb[i];
#pragma unroll
    for (int r = 0; r < 8; ++r) {
      acc[r] = fmaf(trow[r][i], pv, acc[r]);
      bacc[r] = fmaf(trow[r][i], pbv, bacc[r]);
    }
  }
#pragma unroll
  for (int r = 0; r < 8; ++r)
    wt1[(size_t)(o0 + r) * 768 + k] = f2bf(trow[r][k] + 0.3f * acc[r]);
  if (k == 0) {
#pragma unroll
    for (int r = 0; r < 8; ++r)
      b1e[o0 + r] = t1b[o0 + r] + 0.3f * bacc[r];
  }
}

// ---------------------------------------------------------------------------
// bf16 MFMA GEMM: async global_load_lds staging into fragment-ordered LDS.
// BK=64 (two MFMA sub-steps per barrier pair). Single-buffered: at 3-6
// blocks/CU the wave-level TLP already hides staging latency (r7 A/B).
// VSPLIT (in_proj): cols >=512 (V) are written transposed to vt instead.
// ---------------------------------------------------------------------------
enum { EPI_NONE = 0, EPI_GELU = 1, EPI_ADDSCALE = 2 };

template <int EPI, int BM, int BN, bool OUTBF, bool VSPLIT>
__global__ __launch_bounds__(256, 4)
void mgemm(const u16* __restrict__ A, int lda,
           const u16* __restrict__ Wb, int K, const float* __restrict__ bias,
           void* __restrict__ Cv, int ldc, int col_off,
           const float* __restrict__ addsrc, u16* __restrict__ vt) {
  __shared__ u16 As[BM * 64];
  __shared__ u16 Bs[BN * 64];
  const int tid = threadIdx.x;
  const int w = tid >> 6, lane = tid & 63;
  const int ln = lane & 15, quad = lane >> 4;
  const int m0 = blockIdx.x * BM;
  const int n0 = blockIdx.y * BN;
  constexpr int MT = (BM == 128) ? 2 : 1;  // wave rows = 4 waves x (MT*16)
  const int wm = w * (MT * 16);
  constexpr int wn = 0;
  constexpr int APW = BM / 64;  // A 16-row groups per wave per sub-step
  constexpr int BPW = BN / 64;

  f32x4 acc[MT][4] = {};

  const int grow = lane >> 2;      // row within 16-row group
  const int gk8 = (lane & 3) * 8;  // k element offset

  for (int k0 = 0; k0 < K; k0 += 64) {
#pragma unroll
    for (int s = 0; s < 2; ++s) {
#pragma unroll
      for (int p = 0; p < APW; ++p) {
        const int g = w * APW + p;
        glds16(A + (size_t)(m0 + g * 16 + grow) * lda + k0 + s * 32 + gk8,
               As + s * BM * 32 + g * 512);
      }
#pragma unroll
      for (int p = 0; p < BPW; ++p) {
        const int g = w * BPW + p;
        glds16(Wb + (size_t)(n0 + g * 16 + grow) * K + k0 + s * 32 + gk8,
               Bs + s * BN * 32 + g * 512);
      }
    }
    __syncthreads();  // drains vmcnt -> LDS valid
#pragma unroll
    for (int s = 0; s < 2; ++s) {
      const u16* abase = As + s * BM * 32 + (wm >> 4) * 512 + ln * 32 + quad * 8;
      const u16* bbase = Bs + s * BN * 32 + ln * 32 + quad * 8;
      bf16x8 af[MT], bv[4];
#pragma unroll
      for (int i = 0; i < MT; ++i) af[i] = *(const bf16x8*)(abase + i * 512);
#pragma unroll
      for (int j = 0; j < 4; ++j) bv[j] = *(const bf16x8*)(bbase + j * 512);
#pragma unroll
      for (int i = 0; i < MT; ++i)
#pragma unroll
        for (int j = 0; j < 4; ++j)
          acc[i][j] = __builtin_amdgcn_mfma_f32_16x16x32_bf16(af[i], bv[j],
                                                              acc[i][j], 0, 0, 0);
    }
    __syncthreads();  // protect LDS reuse next iter
  }

#pragma unroll
  for (int i = 0; i < MT; ++i)
#pragma unroll
    for (int j = 0; j < 4; ++j) {
      const int col = n0 + wn + j * 16 + ln;
      const float bsv = bias[col];
      const int row0 = m0 + wm + i * 16 + quad * 4;
      float vals[4];
#pragma unroll
      for (int r = 0; r < 4; ++r) {
        float v = acc[i][j][r] + bsv;
        if (EPI == EPI_GELU) v = 0.5f * v * (1.0f + erff(v * 0.70710678f));
        if (EPI == EPI_ADDSCALE)
          v = addsrc[(size_t)(row0 + r) * 256 + col] + 0.3f * v;
        vals[r] = v;
      }
      if (VSPLIT && col >= 512) {
        // V: write transposed vt[(b*256 + (col-512))][t], 4 consecutive t
        ushort4 pk;
        pk.x = f2bf(vals[0]); pk.y = f2bf(vals[1]);
        pk.z = f2bf(vals[2]); pk.w = f2bf(vals[3]);
        *(ushort4*)(vt + (size_t)((row0 >> 10) * 256 + (col - 512)) * T_SZ +
                    (row0 & 1023)) = pk;
      } else if (OUTBF) {
#pragma unroll
        for (int r = 0; r < 4; ++r)
          ((u16*)Cv)[(size_t)(row0 + r) * ldc + col_off + col] = f2bf(vals[r]);
      } else {
#pragma unroll
        for (int r = 0; r < 4; ++r)
          ((float*)Cv)[(size_t)(row0 + r) * ldc + col_off + col] = vals[r];
      }
    }
}

// ---------------------------------------------------------------------------
// Fused GEMM (+add) + LayerNorm epilogue, full-occupancy shape:
// BM=16, BN=256 (full row), grid = 512 blocks. Wave w owns the 64-col slice;
// LN row-reduction = wave-local shfl + one LDS cross-wave combine.
// ---------------------------------------------------------------------------
template <bool WRITE_BF>
__global__ __launch_bounds__(256, 4)
void mgemm_ln16(const u16* __restrict__ A, const u16* __restrict__ Wb, int K,
                const float* __restrict__ bias, const float* __restrict__ addsrc,
                const float* __restrict__ g, const float* __restrict__ bb,
                float* __restrict__ outf, u16* __restrict__ outbf, int bfldc) {
  __shared__ u16 As[2 * 512];     // 2KB: [s][16 rows x 32 k]
  __shared__ u16 Bs[2 * 8192];    // 32KB: [s][16 groups][16 rows x 32 k]
  __shared__ float tS1[4][16], tS2[4][16];
  const int tid = threadIdx.x;
  const int w = tid >> 6, lane = tid & 63;
  const int ln = lane & 15, quad = lane >> 4;
  const int m0 = blockIdx.x * 16;
  const int grow = lane >> 2;      // row within 16-row group
  const int gk8 = (lane & 3) * 8;  // k element offset

  f32x4 acc[4] = {};

  for (int k0 = 0; k0 < K; k0 += 64) {
    // A: wave 0 stages sub-step 0, wave 1 stages sub-step 1
    if (w < 2)
      glds16(A + (size_t)(m0 + grow) * K + k0 + w * 32 + gk8, As + w * 512);
    // B: 32 group-issues (2 sub-steps x 16 groups), 8 per wave
#pragma unroll
    for (int p = 0; p < 8; ++p) {
      const int idx = w * 8 + p;
      const int s = idx >> 4, gg = idx & 15;
      glds16(Wb + (size_t)(gg * 16 + grow) * K + k0 + s * 32 + gk8,
             Bs + s * 8192 + gg * 512);
    }
    __syncthreads();  // drains vmcnt -> LDS valid
#pragma unroll
    for (int s = 0; s < 2; ++s) {
      const bf16x8 af = *(const bf16x8*)(As + s * 512 + ln * 32 + quad * 8);
      const u16* bbase = Bs + s * 8192 + (w * 4) * 512 + ln * 32 + quad * 8;
#pragma unroll
      for (int j = 0; j < 4; ++j) {
        bf16x8 bv = *(const bf16x8*)(bbase + j * 512);
        acc[j] = __builtin_amdgcn_mfma_f32_16x16x32_bf16(af, bv, acc[j], 0, 0, 0);
      }
    }
    __syncthreads();
  }

  // epilogue: add bias + addsrc, accumulate LN stats
  const int row0 = m0 + quad * 4;
  float s1[4] = {}, s2[4] = {};
#pragma unroll
  for (int j = 0; j < 4; ++j) {
    const int col = w * 64 + j * 16 + ln;
    const float bsv = bias[col];
#pragma unroll
    for (int r = 0; r < 4; ++r) {
      float v = acc[j][r] + bsv + addsrc[(size_t)(row0 + r) * 256 + col];
      acc[j][r] = v;
      s1[r] += v;
      s2[r] += v * v;
    }
  }
  // wave-local reduce over the 16 ln lanes (quad = row-parallel)
#pragma unroll
  for (int r = 0; r < 4; ++r) {
#pragma unroll
    for (int o = 8; o > 0; o >>= 1) {
      s1[r] += __shfl_xor(s1[r], o);
      s2[r] += __shfl_xor(s2[r], o);
    }
  }
  if (ln == 0) {
#pragma unroll
    for (int r = 0; r < 4; ++r) {
      tS1[w][quad * 4 + r] = s1[r];
      tS2[w][quad * 4 + r] = s2[r];
    }
  }
  __syncthreads();
  float mean[4], inv[4];
#pragma unroll
  for (int r = 0; r < 4; ++r) {
    const int qr = quad * 4 + r;
    const float S1 = tS1[0][qr] + tS1[1][qr] + tS1[2][qr] + tS1[3][qr];
    const float S2 = tS2[0][qr] + tS2[1][qr] + tS2[2][qr] + tS2[3][qr];
    mean[r] = S1 * (1.f / 256.f);
    const float var = S2 * (1.f / 256.f) - mean[r] * mean[r];
    inv[r] = rsqrtf(var + 1e-5f);
  }
#pragma unroll
  for (int j = 0; j < 4; ++j) {
    const int col = w * 64 + j * 16 + ln;
    const float gc = g[col], bc = bb[col];
#pragma unroll
    for (int r = 0; r < 4; ++r) {
      const float y = (acc[j][r] - mean[r]) * inv[r] * gc + bc;
      outf[(size_t)(row0 + r) * 256 + col] = y;
      if (WRITE_BF) outbf[(size_t)(row0 + r) * bfldc + col] = f2bf(y);
    }
  }
}

// ---------------------------------------------------------------------------
// LDS-staged MFMA flash attention (r6, verified). Block = 4 waves = q-tiles
// 4p..4p+3 of one (b,h): equal causal tile counts, shared K/V, double-
// buffered LDS prefetch, one barrier per tile. p paired with 15-p across
// the grid for constant co-resident work.
// ---------------------------------------------------------------------------
__global__ __launch_bounds__(256)
void attn_flash(const u16* __restrict__ qkv, const u16* __restrict__ vt,
                u16* __restrict__ outp) {
  __shared__ u16 Ks[2][4096];   // [buf][s*2048 + g*512 + row*32 + k8]
  __shared__ u16 Vs[2][4096];
  __shared__ u16 Ps[4][16][72];
  const int tid = threadIdx.x;
  const int w = tid >> 6, lane = tid & 63;
  const int ln = lane & 15, quad = lane >> 4, kq8 = quad * 8;
  const int bid = blockIdx.x;
  const int r0 = bid & 255;
  int bh = r0 >> 4;
  int p = r0 & 15;
  if (bid >> 8) { bh += 16; p = 15 - p; }
  const int qt = p * 4 + w;
  const int q0 = qt * 16;
  const int b = bh >> 2, h = bh & 3;
  const u16* base = qkv + (size_t)b * T_SZ * 768;
  const u16* kbase = base + 256 + h * 64;
  const u16* vbase = vt + (size_t)bh * 64 * T_SZ;
  const int grow = lane >> 2;
  const int gk8 = (lane & 3) * 8;

  bf16x8 qf[2];
#pragma unroll
  for (int ks = 0; ks < 2; ++ks)
    qf[ks] = *(const bf16x8*)(base + (size_t)(q0 + ln) * 768 + h * 64 +
                              ks * 32 + kq8);
  const short ob = (short)0x3F80;
  const bf16x8 ones = {ob, ob, ob, ob, ob, ob, ob, ob};

  const int nt = p + 1;

#define STAGE_KV(jt, buf)                                                     \
  {                                                                           \
    const int c0s = (jt) * 64;                                                \
    const int isV = w >> 1, ss = w & 1;                                       \
    _Pragma("unroll") for (int pg = 0; pg < 4; ++pg) {                        \
      if (!isV)                                                               \
        glds16(kbase + (size_t)(c0s + pg * 16 + grow) * 768 + ss * 32 + gk8,  \
               &Ks[buf][ss * 2048 + pg * 512]);                               \
      else                                                                    \
        glds16(vbase + (size_t)(pg * 16 + grow) * T_SZ + c0s + ss * 32 + gk8, \
               &Vs[buf][ss * 2048 + pg * 512]);                               \
    }                                                                         \
  }

  f32x4 O[4] = {};
  f32x4 l_acc = {};
  int cur = 0;
  STAGE_KV(0, 0);
  for (int jt = 0; jt < nt; ++jt) {
    __syncthreads();
    if (jt + 1 < nt) STAGE_KV(jt + 1, cur ^ 1);
    const int c0 = jt * 64;
    f32x4 sv[4] = {};
#pragma unroll
    for (int ks = 0; ks < 2; ++ks)
#pragma unroll
      for (int j = 0; j < 4; ++j) {
        bf16x8 kf = *(const bf16x8*)&Ks[cur][ks * 2048 + j * 512 + ln * 32 + kq8];
        sv[j] = __builtin_amdgcn_mfma_f32_16x16x32_bf16(qf[ks], kf, sv[j], 0, 0, 0);
      }
    const bool need_mask = (jt == nt - 1);
#pragma unroll
    for (int j = 0; j < 4; ++j)
#pragma unroll
      for (int r = 0; r < 4; ++r) {
        float pv = __expf(sv[j][r] * 0.125f);
        if (need_mask && (c0 + j * 16 + ln > q0 + quad * 4 + r)) pv = 0.f;
        Ps[w][quad * 4 + r][j * 16 + ln] = f2bf(pv);
      }
#pragma unroll
    for (int ks = 0; ks < 2; ++ks) {
      bf16x8 pf = *(const bf16x8*)&Ps[w][ln][ks * 32 + kq8];
      l_acc = __builtin_amdgcn_mfma_f32_16x16x32_bf16(pf, ones, l_acc, 0, 0, 0);
#pragma unroll
      for (int j = 0; j < 4; ++j) {
        bf16x8 vf = *(const bf16x8*)&Vs[cur][ks * 2048 + j * 512 + ln * 32 + kq8];
        O[j] = __builtin_amdgcn_mfma_f32_16x16x32_bf16(pf, vf, O[j], 0, 0, 0);
      }
    }
    cur ^= 1;
  }
#undef STAGE_KV

  u16* op = outp + (size_t)b * T_SZ * 256;
#pragma unroll
  for (int r = 0; r < 4; ++r) {
    const float inv = 1.f / l_acc[r];
#pragma unroll
    for (int j = 0; j < 4; ++j)
      op[(size_t)(q0 + quad * 4 + r) * 256 + h * 64 + j * 16 + ln] =
          f2bf(O[j][r] * inv);
  }
}

// ---------------------------------------------------------------------------
// block reduction helpers (fp32)
// ---------------------------------------------------------------------------
__device__ __forceinline__ void block_reduce_2(float& a, float& q, float* tmp) {
#pragma unroll
  for (int o = 32; o > 0; o >>= 1) {
    a += __shfl_down(a, o);
    q += __shfl_down(q, o);
  }
  const int lane = threadIdx.x & 63, wid = threadIdx.x >> 6;
  if (lane == 0) { tmp[wid] = a; tmp[4 + wid] = q; }
  __syncthreads();
  a = tmp[0] + tmp[1] + tmp[2] + tmp[3];
  q = tmp[4] + tmp[5] + tmp[6] + tmp[7];
  __syncthreads();
}

__device__ __forceinline__ float ln_finish(float v, float s1, float s2,
                                           float g, float bb) {
  float mean = s1 * (1.f / 256.f);
  float var = s2 * (1.f / 256.f) - mean * mean;
  return (v - mean) * rsqrtf(var + 1e-5f) * g + bb;
}

// ---------------------------------------------------------------------------
// Fused depthwise conv (window 8) + EMA local pass.
// ---------------------------------------------------------------------------
__global__ __launch_bounds__(256)
void emaconv_kernel(const float* __restrict__ x, const float* __restrict__ cw,
                    const float* __restrict__ cb, u16* __restrict__ comb,
                    float* __restrict__ scr) {
  const int bc = blockIdx.x;
  const int b = bc >> 5, ch = bc & 31;
  const int d = threadIdx.x;
  const int t0 = ch * 32;
  float wreg[8];
#pragma unroll
  for (int j = 0; j < 8; ++j) wreg[j] = cw[d * 8 + j];
  const float bias = cb[d];
  float xw[8];
#pragma unroll
  for (int j = 0; j < 7; ++j) {
    const int ts = t0 - 7 + j;
    xw[j] = (ts >= 0) ? x[(size_t)(b * T_SZ + ts) * 256 + d] : 0.f;
  }
  float c = 0.f;
#pragma unroll
  for (int tl = 0; tl < 32; ++tl) {
    const size_t row = (size_t)(b * T_SZ + t0 + tl);
    xw[7] = x[row * 256 + d];
    float conv = bias;
#pragma unroll
    for (int j = 0; j < 8; ++j) conv = fmaf(xw[j], wreg[j], conv);
    c = 0.9f * c + 0.1f * xw[7];
    comb[row * 768 + 256 + d] = f2bf(conv);
    comb[row * 768 + 512 + d] = f2bf(c);
#pragma unroll
    for (int j = 0; j < 7; ++j) xw[j] = xw[j + 1];
  }
  scr[(size_t)bc * 256 + d] = c;
}

__global__ __launch_bounds__(256)
void ema_b_kernel(float* __restrict__ scr) {
  const int b = blockIdx.x, d = threadIdx.x;
  const float q32 = 0.03433683820292512f;  // 0.9^32
  float carry = 0.f;
  for (int ch = 0; ch < 32; ++ch) {
    const size_t idx = (size_t)(b * 32 + ch) * 256 + d;
    float e = scr[idx];
    scr[idx] = carry;
    carry = e + q32 * carry;
  }
}

// vectorized finalize: 4 rows/block (ushort4/float4), 2048 blocks.
// (verified correct + passing in the r8 run; pure BW improvement)
__global__ __launch_bounds__(256)
void ema_c_kernel(u16* __restrict__ comb, const float* __restrict__ scr,
                  float* __restrict__ fts) {
  const int row = blockIdx.x * 4 + (threadIdx.x >> 6);
  const int d4 = (threadIdx.x & 63) * 4;
  const int b = row >> 10, t = row & 1023;
  const int ch = t >> 5, tl = t & 31;
  const float4 cv = *(const float4*)(scr + (size_t)(b * 32 + ch) * 256 + d4);
  const float pw = __powf(0.9f, (float)(tl + 1));
  u16* cp = comb + (size_t)row * 768 + 512 + d4;
  ushort4 lv = *(ushort4*)cp;
  float y0 = fmaf(pw, cv.x, bf2f(lv.x));
  float y1 = fmaf(pw, cv.y, bf2f(lv.y));
  float y2 = fmaf(pw, cv.z, bf2f(lv.z));
  float y3 = fmaf(pw, cv.w, bf2f(lv.w));
  ushort4 ov;
  ov.x = f2bf(y0); ov.y = f2bf(y1); ov.z = f2bf(y2); ov.w = f2bf(y3);
  *(ushort4*)cp = ov;
  if (t == 1023) {  // wave-uniform branch
    float4 fo;
    fo.x = y0; fo.y = y1; fo.z = y2; fo.w = y3;
    *(float4*)(fts + b * 256 + d4) = fo;
  }
}

__global__ __launch_bounds__(256)
void cs_a_kernel(float* __restrict__ deltas, float* __restrict__ scr) {
  const int bc = blockIdx.x;
  const int b = bc >> 5, ch = bc & 31;
  const int d = threadIdx.x;
  const int t0 = ch * 32;
  float c = 0.f;
  for (int tl = 0; tl < 32; ++tl) {
    const size_t idx = (size_t)(b * T_SZ + t0 + tl) * 256 + d;
    c += deltas[idx];
    deltas[idx] = c;
  }
  scr[(size_t)bc * 256 + d] = c;
}

__global__ __launch_bounds__(256)
void cs_b_kernel(float* __restrict__ scr) {
  const int b = blockIdx.x, d = threadIdx.x;
  float carry = 0.f;
  for (int ch = 0; ch < 32; ++ch) {
    const size_t idx = (size_t)(b * 32 + ch) * 256 + d;
    float e = scr[idx];
    scr[idx] = carry;
    carry += e;
  }
}

// states = LN3(seq + 0.5*(chunk_cumsum + carry)); the t==1023 block also
// computes fss = LN4(states row) in-place (block-uniform branch).
__global__ __launch_bounds__(256)
void ln3_states_kernel(const float* __restrict__ deltas, const float* __restrict__ scr,
                       const float* __restrict__ seq, const float* __restrict__ g3,
                       const float* __restrict__ b3, const float* __restrict__ g4,
                       const float* __restrict__ b4, u16* __restrict__ st,
                       float* __restrict__ fss) {
  __shared__ float tmp[8];
  const int row = blockIdx.x;
  const int b = row >> 10, t = row & 1023;
  const int d = threadIdx.x;
  float v = seq[b * 256 + d] +
            0.5f * (deltas[(size_t)row * 256 + d] +
                    scr[(size_t)(b * 32 + (t >> 5)) * 256 + d]);
  float a = v, q = v * v;
  block_reduce_2(a, q, tmp);
  const float y = ln_finish(v, a, q, g3[d], b3[d]);
  st[(size_t)row * 256 + d] = f2bf(y);
  if (t == 1023) {
    float a2 = y, q2 = y * y;
    block_reduce_2(a2, q2, tmp);
    fss[b * 256 + d] = ln_finish(y, a2, q2, g4[d], b4[d]);
  }
}

// ---------------------------------------------------------------------------
extern "C" void kernel_launch(void* const* d_in, const int* in_sizes, int n_in,
                              void* d_out, int out_size, void* d_ws,
                              size_t ws_size, hipStream_t stream) {
  (void)in_sizes; (void)n_in; (void)out_size; (void)ws_size;
  const float* parallel_repr = (const float*)d_in[0];
  const float* sequential_state = (const float*)d_in[1];
  const float* in_proj_b = (const float*)d_in[4];
  const float* out_proj_b = (const float*)d_in[6];
  const float* conv_w = (const float*)d_in[7];
  const float* conv_b = (const float*)d_in[8];
  const float* p2s_w_f = (const float*)d_in[9];
  const float* p2s_b = (const float*)d_in[10];
  const float* s2p_b = (const float*)d_in[12];
  const float* trans_w1_f = (const float*)d_in[13];
  const float* trans_b1 = (const float*)d_in[14];
  const float* trans_b2 = (const float*)d_in[16];
  const float* ffn_b1 = (const float*)d_in[18];
  const float* ffn_b2 = (const float*)d_in[20];
  const float* ln1_s = (const float*)d_in[21];
  const float* ln1_b = (const float*)d_in[22];
  const float* ln2_s = (const float*)d_in[23];
  const float* ln2_b = (const float*)d_in[24];
  const float* ln3_s = (const float*)d_in[25];
  const float* ln3_b = (const float*)d_in[26];
  const float* ln4_s = (const float*)d_in[27];
  const float* ln4_b = (const float*)d_in[28];

  char* ws = (char*)d_ws;
  u16* qkv_bf = (u16*)(ws + OFF_QKV);
  u16* attn_bf = (u16*)(ws + OFF_ATTN);
  u16* states_bf = (u16*)(ws + OFF_ATTN);
  u16* f_bf = (u16*)(ws + OFF_F);
  float* x = (float*)(ws + OFF_X);
  u16* comb = (u16*)(ws + OFF_COMB);
  u16* pr_bf = (u16*)(ws + OFF_COMB);  // dead before comb is written
  float* fbuf = (float*)(ws + OFF_FB);
  u16* vt = (u16*)(ws + OFF_H);        // dead before h is written
  u16* h_bf = (u16*)(ws + OFF_H);
  u16* ffn_in = (u16*)(ws + OFF_XBF);
  u16* wb = (u16*)(ws + OFF_WB);
  float* scr1 = (float*)(ws + OFF_SCR1);
  float* scr2 = (float*)(ws + OFF_SCR2);
  float* b1e = (float*)(ws + OFF_B1E);
  float* out = (float*)d_out;
  float* out_fss = out + S_ELT;
  float* out_fts = out + S_ELT + 2048;

  const dim3 blk(256);

  // 0. weights + parallel_repr -> bf16
  wconv_kernel<<<3456, blk, 0, stream>>>(
      (const float*)d_in[3], (const float*)d_in[5], (const float*)d_in[9],
      (const float*)d_in[11], (const float*)d_in[13], (const float*)d_in[15],
      (const float*)d_in[17], (const float*)d_in[19], parallel_repr, wb, pr_bf);
  // 0b. fold p2s into trans_w1's x-columns (+ bias fold)
  wfold_kernel<<<64, blk, 0, stream>>>(trans_w1_f, p2s_w_f, trans_b1, p2s_b,
                                       wb + WB_T1, b1e);
  // 1. qkv = PR @ in_proj^T + b; V columns written transposed to vt
  mgemm<EPI_NONE, 128, 64, true, true><<<dim3(64, 12), blk, 0, stream>>>(
      pr_bf, 256, wb + WB_INPROJ, 256, in_proj_b, qkv_bf, 768, 0, nullptr, vt);
  // 2. attention (LDS double-buffered K/V prefetch, 4 q-tiles/block)
  attn_flash<<<512, blk, 0, stream>>>(qkv_bf, vt, attn_bf);
  // 3. x = LN1(PR + attn @ out_proj^T + b) -> x fp32 + bf16 mirror into
  //    comb[:,0:256] (p2s fold makes this the correct trans1 input)
  mgemm_ln16<true><<<512, blk, 0, stream>>>(
      attn_bf, wb + WB_OUTPROJ, 256, out_proj_b, parallel_repr, ln1_s, ln1_b,
      x, comb, 768);
  // 4-6. fused conv+EMA -> comb[:,256:768] + traj summary
  emaconv_kernel<<<256, blk, 0, stream>>>(x, conv_w, conv_b, comb, scr1);
  ema_b_kernel<<<8, blk, 0, stream>>>(scr1);
  ema_c_kernel<<<2048, blk, 0, stream>>>(comb, scr1, out_fts);
  // 7. h = gelu(comb @ W1eff^T + b1eff)  (p2s GEMM folded away)
  mgemm<EPI_GELU, 128, 64, true, false><<<dim3(64, 8), blk, 0, stream>>>(
      comb, 768, wb + WB_T1, 768, b1e, h_bf, 512, 0, nullptr, nullptr);
  // 8. deltas = h @ t2^T + b2 -> fbuf (fp32)
  mgemm<EPI_NONE, 64, 64, false, false><<<dim3(128, 4), blk, 0, stream>>>(
      h_bf, 512, wb + WB_T2, 512, trans_b2, fbuf, 256, 0, nullptr, nullptr);
  // 9-10. cumsum
  cs_a_kernel<<<256, blk, 0, stream>>>(fbuf, scr2);
  cs_b_kernel<<<8, blk, 0, stream>>>(scr2);
  // 11. states = LN3(...) -> bf16; t==1023 blocks also emit fss = LN4
  ln3_states_kernel<<<8192, blk, 0, stream>>>(fbuf, scr2, sequential_state,
                                              ln3_s, ln3_b, ln4_s, ln4_b,
                                              states_bf, out_fss);
  // 12. ffn_in = x + 0.3*(states @ s2p^T + b)
  mgemm<EPI_ADDSCALE, 64, 64, true, false><<<dim3(128, 4), blk, 0, stream>>>(
      states_bf, 256, wb + WB_S2P, 256, s2p_b, ffn_in, 256, 0, x, nullptr);
  // 13. f = gelu(ffn_in @ ffn1^T + b1)
  mgemm<EPI_GELU, 128, 64, true, false><<<dim3(64, 16), blk, 0, stream>>>(
      ffn_in, 256, wb + WB_F1, 256, ffn_b1, f_bf, 1024, 0, nullptr, nullptr);
  // 14. out = LN2(x + f @ ffn2^T + b2), fused GEMM+LN
  mgemm_ln16<false><<<512, blk, 0, stream>>>(
      f_bf, wb + WB_F2, 1024, ffn_b2, x, ln2_s, ln2_b, out, nullptr, 256);
}